// Round 13
// baseline (194.545 us; speedup 1.0000x reference)
//
#include <hip/hip_runtime.h>
#include <math.h>

typedef short bf16x8 __attribute__((ext_vector_type(8)));
typedef float f32x4  __attribute__((ext_vector_type(4)));

// round-to-nearest-even float -> bf16 bits
__device__ __forceinline__ unsigned short f2bf(float x) {
    unsigned int u = __float_as_uint(x);
    return (unsigned short)((u + 0x7FFFu + ((u >> 16) & 1u)) >> 16);
}
__device__ __forceinline__ float bf2f(unsigned short h) {
    return __uint_as_float(((unsigned int)h) << 16);
}
// RNE split (precompute path)
__device__ __forceinline__ void split2(float x, unsigned short& h, unsigned short& l) {
    h = f2bf(x);
    l = f2bf(x - bf2f(h));
}
// truncation split (hot path): hi = trunc(x), lo = RNE(x-hi); combined rel err ~2^-17
__device__ __forceinline__ void split2t(float x, unsigned short& h, unsigned short& l) {
    unsigned int u = __float_as_uint(x);
    h = (unsigned short)(u >> 16);
    float r = x - __uint_as_float(u & 0xFFFF0000u);
    l = f2bf(r);
}

// XOR-swizzled H index within a 16-row strip (shorts, row stride 72).
// Write (row=q*4+r, col=nt*16+c16): 16B-block ^ q -> each q-group lands in a
// disjoint 8-bank window, 2 shorts/bank (free). b128 reads stay 16B-aligned.
__device__ __forceinline__ int hsw(int row, int col) {
    return row * 72 + ((((col >> 3) ^ ((row >> 2) & 3)) << 3) | (col & 7));
}

__device__ __forceinline__ float inv_norm3(float x, float y, float z) {
    float d = fmaf(x, x, fmaf(y, y, z * z));
    return rsqrtf(fmaxf(d, 1e-24f));
}
__device__ __forceinline__ float3 f3sub(float3 a, float3 b) {
    return make_float3(a.x - b.x, a.y - b.y, a.z - b.z);
}
__device__ __forceinline__ float3 f3cross(float3 a, float3 b) {
    return make_float3(a.y * b.z - a.z * b.y,
                       a.z * b.x - a.x * b.z,
                       a.x * b.y - a.y * b.x);
}
// NeRF frame, parallel normalizations (n from unnormalized w: same direction)
__device__ __forceinline__ void nerf_frame(const float3& A, const float3& Bv,
                                           const float3& C, float3& bc,
                                           float3& n, float3& m3) {
    float3 w  = f3sub(C, Bv);
    float3 v  = f3sub(Bv, A);
    float3 cr = f3cross(v, w);
    float iw = inv_norm3(w.x, w.y, w.z);
    float ic = inv_norm3(cr.x, cr.y, cr.z);
    bc = make_float3(w.x * iw, w.y * iw, w.z * iw);
    n  = make_float3(cr.x * ic, cr.y * ic, cr.z * ic);
    m3 = f3cross(n, bc);
}
__device__ __forceinline__ float3 nerf_place(const float3& C, const float3& bc,
                                             const float3& m3, const float3& n,
                                             float tx, float ty, float tz) {
    return make_float3(
        fmaf(m3.x, ty, fmaf(bc.x, tx, fmaf(n.x, tz, C.x))),
        fmaf(m3.y, ty, fmaf(bc.y, tx, fmaf(n.y, tz, C.y))),
        fmaf(m3.z, ty, fmaf(bc.z, tx, fmaf(n.z, tz, C.z))));
}

struct KParams {
    const int* seq; const int* kmer; const float* pssm;
    const float* se; const float* emb;
    const float* W0; const float* b0; const float* We; const float* be;
    const float* W1; const float* b1;
    float* kmerT; float* seqT; float* srf_t; float* fragbuf;
    float4* frames; float* FPbuf; float* out;
    unsigned short *WeTH, *WeTL, *W0pTH, *W0pTL, *W1TH, *W1TL;
};

// ======== tables: kmerT via split-bf16 MFMA (vector loads), seqT, weight tables
__global__ __launch_bounds__(256) void tables_kernel(KParams P) {
    const int tid = threadIdx.x;
    const int vb  = blockIdx.x;
    if (vb < 167) {
        const int lane = tid & 63;
        const int wv   = __builtin_amdgcn_readfirstlane(tid >> 6);
        const int q    = lane >> 4;
        const int c16  = lane & 15;
        const int r0   = vb * 64;
        const int n    = wv * 16 + c16;

        bf16x8 BH[8], BL[8];
        #pragma unroll
        for (int kt8 = 0; kt8 < 8; ++kt8)
            #pragma unroll
            for (int j = 0; j < 8; ++j) {
                float w = P.W0[(16 + kt8 * 32 + q * 8 + j) * 64 + n];
                unsigned short h, l; split2t(w, h, l);
                BH[kt8][j] = (short)h; BL[kt8][j] = (short)l;
            }
        f32x4 acc[4];
        #pragma unroll
        for (int t = 0; t < 4; ++t) acc[t] = (f32x4){0.f, 0.f, 0.f, 0.f};
        #pragma unroll
        for (int kt8 = 0; kt8 < 8; ++kt8) {
            #pragma unroll
            for (int t = 0; t < 4; ++t) {
                int rr = r0 + t * 16 + c16;
                if (rr > 10647) rr = 10647;
                const float* ap = P.emb + rr * 256 + kt8 * 32 + q * 8;
                float4 a0 = *(const float4*)ap;
                float4 a1 = *(const float4*)(ap + 4);
                bf16x8 ah, al;
                unsigned short h, l;
                split2t(a0.x, h, l); ah[0] = (short)h; al[0] = (short)l;
                split2t(a0.y, h, l); ah[1] = (short)h; al[1] = (short)l;
                split2t(a0.z, h, l); ah[2] = (short)h; al[2] = (short)l;
                split2t(a0.w, h, l); ah[3] = (short)h; al[3] = (short)l;
                split2t(a1.x, h, l); ah[4] = (short)h; al[4] = (short)l;
                split2t(a1.y, h, l); ah[5] = (short)h; al[5] = (short)l;
                split2t(a1.z, h, l); ah[6] = (short)h; al[6] = (short)l;
                split2t(a1.w, h, l); ah[7] = (short)h; al[7] = (short)l;
                acc[t] = __builtin_amdgcn_mfma_f32_16x16x32_bf16(ah, BH[kt8], acc[t], 0, 0, 0);
                acc[t] = __builtin_amdgcn_mfma_f32_16x16x32_bf16(al, BH[kt8], acc[t], 0, 0, 0);
                acc[t] = __builtin_amdgcn_mfma_f32_16x16x32_bf16(ah, BL[kt8], acc[t], 0, 0, 0);
            }
        }
        #pragma unroll
        for (int t = 0; t < 4; ++t)
            #pragma unroll
            for (int r = 0; r < 4; ++r) {
                int row = r0 + t * 16 + q * 4 + r;
                if (row < 10648) P.kmerT[row * 64 + n] = acc[t][r];
            }
    } else if (vb < 172) {
        // seqT[r][j] = seq_embed[r]@W0[0:16] + b0[j] + 0.5*sum_c W0p[c][j]
        int e = (vb - 167) * 256 + tid;
        int r = e >> 6, j = e & 63;
        float acc = P.b0[j];
        #pragma unroll
        for (int k = 0; k < 16; ++k)
            acc = fmaf(P.se[r * 16 + k], P.W0[k * 64 + j], acc);
        float cs = 0.f;
        #pragma unroll
        for (int c = 0; c < 21; ++c) cs += P.W0[(272 + c) * 64 + j];
        P.seqT[r * 64 + j] = acc + 0.5f * cs;
    } else {
        #pragma unroll
        for (int i = 0; i < 16; ++i) {
            int e = i * 256 + tid;
            int k = e >> 6, n = e & 63;
            unsigned short h, l; split2(P.We[k * 64 + n], h, l);
            P.WeTH[n * 64 + k] = h; P.WeTL[n * 64 + k] = l;
        }
        #pragma unroll
        for (int i = 0; i < 8; ++i) {
            int e = i * 256 + tid;
            int k = e >> 6, n = e & 63;
            float w = (k < 21) ? P.W0[(272 + k) * 64 + n] : 0.f;
            unsigned short h, l; split2(w, h, l);
            P.W0pTH[n * 32 + k] = h; P.W0pTL[n * 32 + k] = l;
        }
        #pragma unroll
        for (int i = 0; i < 4; ++i) {
            int e = i * 256 + tid;
            int k = e >> 4, c = e & 15;
            float w = (c < 9) ? P.W1[k * 9 + c] : 0.f;
            unsigned short h, l; split2(w, h, l);
            P.W1TH[c * 64 + k] = h; P.W1TL[c * 64 + k] = l;
        }
    }
}

// ======== wave-synchronous split-bf16 MFMA MLP (M-strip per wave) ========
// Wave wv owns positions [m0+16wv, m0+16wv+16) through the ENTIRE pipeline:
// layer l+1's A-operand rows are exactly the C-rows this wave computed, so
// the H round-trip is wave-private. ZERO __syncthreads; per-wave LDS
// ping-pong buffers; LDS b128 reads drop 44 -> 14 per wave.
__global__ __launch_bounds__(256, 4) void mlp_kernel(KParams P) {
    // [buf][wave][hi/lo][row][col] : 2*4*2*16*72*2B = 36864 B
    __shared__ __align__(16) unsigned short Hbuf[2][4][2][16][72];

    const int tid  = threadIdx.x;
    const int lane = tid & 63;
    const int wv   = __builtin_amdgcn_readfirstlane(tid >> 6);
    const int q    = lane >> 4;
    const int c16  = lane & 15;
    const int m0s  = blockIdx.x * 64 + wv * 16;   // wave's strip base position

    unsigned short (*Ah)[72] = Hbuf[0][wv][0];    // buffer A (h0, h2)
    unsigned short (*Al)[72] = Hbuf[0][wv][1];
    unsigned short (*Bh)[72] = Hbuf[1][wv][0];    // buffer B (pssm, h1)
    unsigned short (*Bl)[72] = Hbuf[1][wv][1];
    unsigned short (*Ph)[40] = (unsigned short (*)[40])&Bh[0][0];  // pssm overlay
    unsigned short (*Pl)[40] = (unsigned short (*)[40])&Bl[0][0];

    // ---- indices + gathers: issue first (longest latency) ----
    int sidx[4], kidx[4];
    #pragma unroll
    for (int r = 0; r < 4; ++r) {
        sidx[r] = P.seq[m0s + q * 4 + r];        // 16 distinct addrs/wave, L1
        kidx[r] = P.kmer[m0s + q * 4 + r];
    }
    float g[4][4];
    #pragma unroll
    for (int nt = 0; nt < 4; ++nt)
        #pragma unroll
        for (int r = 0; r < 4; ++r)
            g[nt][r] = P.seqT[sidx[r] * 64 + nt * 16 + c16]
                     + P.kmerT[kidx[r] * 64 + nt * 16 + c16];

    // ---- stage own strip's pssm (centered, trunc-split) into buffer B ----
    for (int i = lane; i < 16 * 21; i += 64) {
        float v = P.pssm[(m0s + i / 21) * 21 + i % 21] - 0.5f;
        unsigned short h, l; split2t(v, h, l);
        Ph[i / 21][i % 21] = h;
        Pl[i / 21][i % 21] = l;
    }
    for (int i = lane; i < 16 * 11; i += 64) {
        Ph[i / 11][21 + (i % 11)] = 0;
        Pl[i / 11][21 + (i % 11)] = 0;
    }

    // ---- layer 0: A = own pssm strip, B = W0p (4 N-tiles) ----
    f32x4 acc[4];
    {
        bf16x8 W0H[4], W0L[4];
        #pragma unroll
        for (int nt = 0; nt < 4; ++nt) {
            W0H[nt] = *(const bf16x8*)(P.W0pTH + (nt * 16 + c16) * 32 + q * 8);
            W0L[nt] = *(const bf16x8*)(P.W0pTL + (nt * 16 + c16) * 32 + q * 8);
        }
        bf16x8 pah = *(const bf16x8*)&Ph[c16][q * 8];   // A row = lane&15
        bf16x8 pal = *(const bf16x8*)&Pl[c16][q * 8];
        #pragma unroll
        for (int nt = 0; nt < 4; ++nt) {
            acc[nt] = (f32x4){0.f, 0.f, 0.f, 0.f};
            acc[nt] = __builtin_amdgcn_mfma_f32_16x16x32_bf16(pah, W0H[nt], acc[nt], 0, 0, 0);
            acc[nt] = __builtin_amdgcn_mfma_f32_16x16x32_bf16(pal, W0H[nt], acc[nt], 0, 0, 0);
            acc[nt] = __builtin_amdgcn_mfma_f32_16x16x32_bf16(pah, W0L[nt], acc[nt], 0, 0, 0);
        }
    }
    // add exact fp32 gathers late; split-store h0 -> buffer A
    #pragma unroll
    for (int nt = 0; nt < 4; ++nt)
        #pragma unroll
        for (int r = 0; r < 4; ++r) {
            unsigned short h, l; split2t(acc[nt][r] + g[nt][r], h, l);
            int idx = hsw(q * 4 + r, nt * 16 + c16);
            (&Ah[0][0])[idx] = h;
            (&Al[0][0])[idx] = l;
        }

    // ---- We fragments (loaded after layer0 to cap VGPR pressure) ----
    bf16x8 WeH[4][2], WeL[4][2];
    #pragma unroll
    for (int nt = 0; nt < 4; ++nt)
        #pragma unroll
        for (int kk = 0; kk < 2; ++kk) {
            WeH[nt][kk] = *(const bf16x8*)(P.WeTH + (nt * 16 + c16) * 64 + kk * 32 + q * 8);
            WeL[nt][kk] = *(const bf16x8*)(P.WeTL + (nt * 16 + c16) * 64 + kk * 32 + q * 8);
        }
    float bias[4];
    #pragma unroll
    for (int nt = 0; nt < 4; ++nt) bias[nt] = P.be[nt * 16 + c16];

    // ---- layer 1: read A (own strip), write B (relu) ----
    {
        bf16x8 a0h = *(const bf16x8*)&(&Ah[0][0])[hsw(c16, q * 8)];
        bf16x8 a0l = *(const bf16x8*)&(&Al[0][0])[hsw(c16, q * 8)];
        bf16x8 a1h = *(const bf16x8*)&(&Ah[0][0])[hsw(c16, 32 + q * 8)];
        bf16x8 a1l = *(const bf16x8*)&(&Al[0][0])[hsw(c16, 32 + q * 8)];
        #pragma unroll
        for (int nt = 0; nt < 4; ++nt) {
            f32x4 a = (f32x4){bias[nt], bias[nt], bias[nt], bias[nt]};
            a = __builtin_amdgcn_mfma_f32_16x16x32_bf16(a0h, WeH[nt][0], a, 0, 0, 0);
            a = __builtin_amdgcn_mfma_f32_16x16x32_bf16(a0l, WeH[nt][0], a, 0, 0, 0);
            a = __builtin_amdgcn_mfma_f32_16x16x32_bf16(a0h, WeL[nt][0], a, 0, 0, 0);
            a = __builtin_amdgcn_mfma_f32_16x16x32_bf16(a1h, WeH[nt][1], a, 0, 0, 0);
            a = __builtin_amdgcn_mfma_f32_16x16x32_bf16(a1l, WeH[nt][1], a, 0, 0, 0);
            a = __builtin_amdgcn_mfma_f32_16x16x32_bf16(a1h, WeL[nt][1], a, 0, 0, 0);
            acc[nt] = (f32x4){fmaxf(a[0], 0.f), fmaxf(a[1], 0.f),
                              fmaxf(a[2], 0.f), fmaxf(a[3], 0.f)};
        }
        #pragma unroll
        for (int nt = 0; nt < 4; ++nt)
            #pragma unroll
            for (int r = 0; r < 4; ++r) {
                unsigned short h, l; split2t(acc[nt][r], h, l);
                int idx = hsw(q * 4 + r, nt * 16 + c16);
                (&Bh[0][0])[idx] = h;
                (&Bl[0][0])[idx] = l;
            }
    }
    // ---- layer 2: read B, write A (relu) ----
    {
        bf16x8 a0h = *(const bf16x8*)&(&Bh[0][0])[hsw(c16, q * 8)];
        bf16x8 a0l = *(const bf16x8*)&(&Bl[0][0])[hsw(c16, q * 8)];
        bf16x8 a1h = *(const bf16x8*)&(&Bh[0][0])[hsw(c16, 32 + q * 8)];
        bf16x8 a1l = *(const bf16x8*)&(&Bl[0][0])[hsw(c16, 32 + q * 8)];
        #pragma unroll
        for (int nt = 0; nt < 4; ++nt) {
            f32x4 a = (f32x4){bias[nt], bias[nt], bias[nt], bias[nt]};
            a = __builtin_amdgcn_mfma_f32_16x16x32_bf16(a0h, WeH[nt][0], a, 0, 0, 0);
            a = __builtin_amdgcn_mfma_f32_16x16x32_bf16(a0l, WeH[nt][0], a, 0, 0, 0);
            a = __builtin_amdgcn_mfma_f32_16x16x32_bf16(a0h, WeL[nt][0], a, 0, 0, 0);
            a = __builtin_amdgcn_mfma_f32_16x16x32_bf16(a1h, WeH[nt][1], a, 0, 0, 0);
            a = __builtin_amdgcn_mfma_f32_16x16x32_bf16(a1l, WeH[nt][1], a, 0, 0, 0);
            a = __builtin_amdgcn_mfma_f32_16x16x32_bf16(a1h, WeL[nt][1], a, 0, 0, 0);
            acc[nt] = (f32x4){fmaxf(a[0], 0.f), fmaxf(a[1], 0.f),
                              fmaxf(a[2], 0.f), fmaxf(a[3], 0.f)};
        }
        #pragma unroll
        for (int nt = 0; nt < 4; ++nt)
            #pragma unroll
            for (int r = 0; r < 4; ++r) {
                unsigned short h, l; split2t(acc[nt][r], h, l);
                int idx = hsw(q * 4 + r, nt * 16 + c16);
                (&Ah[0][0])[idx] = h;
                (&Al[0][0])[idx] = l;
            }
    }
    // ---- head: own strip x 9 outputs (W1 cols padded to 16) ----
    {
        bf16x8 a0h = *(const bf16x8*)&(&Ah[0][0])[hsw(c16, q * 8)];
        bf16x8 a0l = *(const bf16x8*)&(&Al[0][0])[hsw(c16, q * 8)];
        bf16x8 a1h = *(const bf16x8*)&(&Ah[0][0])[hsw(c16, 32 + q * 8)];
        bf16x8 a1l = *(const bf16x8*)&(&Al[0][0])[hsw(c16, 32 + q * 8)];
        bf16x8 W1H0 = *(const bf16x8*)(P.W1TH + c16 * 64 + q * 8);
        bf16x8 W1L0 = *(const bf16x8*)(P.W1TL + c16 * 64 + q * 8);
        bf16x8 W1H1 = *(const bf16x8*)(P.W1TH + c16 * 64 + 32 + q * 8);
        bf16x8 W1L1 = *(const bf16x8*)(P.W1TL + c16 * 64 + 32 + q * 8);
        float b1h = (c16 < 9) ? P.b1[c16] : 0.f;
        f32x4 a = (f32x4){b1h, b1h, b1h, b1h};
        a = __builtin_amdgcn_mfma_f32_16x16x32_bf16(a0h, W1H0, a, 0, 0, 0);
        a = __builtin_amdgcn_mfma_f32_16x16x32_bf16(a0l, W1H0, a, 0, 0, 0);
        a = __builtin_amdgcn_mfma_f32_16x16x32_bf16(a0h, W1L0, a, 0, 0, 0);
        a = __builtin_amdgcn_mfma_f32_16x16x32_bf16(a1h, W1H1, a, 0, 0, 0);
        a = __builtin_amdgcn_mfma_f32_16x16x32_bf16(a1l, W1H1, a, 0, 0, 0);
        a = __builtin_amdgcn_mfma_f32_16x16x32_bf16(a1h, W1L1, a, 0, 0, 0);
        if (c16 < 9) {
            #pragma unroll
            for (int r = 0; r < 4; ++r) {
                int pos = m0s + q * 4 + r;
                int l = pos >> 8, b = pos & 255;
                P.srf_t[(l * 9 + c16) * 256 + b] = a[r];
            }
        }
    }
}

// ======== extend: depth-3 prefetch; emits per-fragment frame + endpoint ========
__global__ __launch_bounds__(64) void extend_kernel(KParams P) {
    int frag = blockIdx.x >> 2;
    int bb   = ((blockIdx.x & 3) << 6) + threadIdx.x;

    float3 A  = make_float3(-0.70710678118654752f, 1.22474487139158905f, 0.f);
    float3 Bv = make_float3(-1.41421356237309505f, 0.f, 0.f);
    float3 C  = make_float3(0.f, 0.f, 0.f);

    float ct0[9], ct1[9], ct2[9], ct3[9];
    #pragma unroll
    for (int m = 0; m < 9; ++m) {
        ct0[m] = P.srf_t[((frag * 32 + 0) * 9 + m) * 256 + bb];
        ct1[m] = P.srf_t[((frag * 32 + 1) * 9 + m) * 256 + bb];
        ct2[m] = P.srf_t[((frag * 32 + 2) * 9 + m) * 256 + bb];
    }
    for (int ll = 0; ll < 32; ++ll) {
        if (ll < 29) {
            #pragma unroll
            for (int m = 0; m < 9; ++m)
                ct3[m] = P.srf_t[((frag * 32 + ll + 3) * 9 + m) * 256 + bb];
        } else {
            #pragma unroll
            for (int m = 0; m < 9; ++m) ct3[m] = 0.f;
        }
        #pragma unroll
        for (int s3 = 0; s3 < 3; ++s3) {
            float3 bc, nn, m3;
            nerf_frame(A, Bv, C, bc, nn, m3);
            float3 d = nerf_place(C, bc, m3, nn,
                                  ct0[3 * s3 + 0], ct0[3 * s3 + 1], ct0[3 * s3 + 2]);
            int row = frag * 96 + ll * 3 + s3;
            P.fragbuf[(row * 3 + 0) * 256 + bb] = d.x;
            P.fragbuf[(row * 3 + 1) * 256 + bb] = d.y;
            P.fragbuf[(row * 3 + 2) * 256 + bb] = d.z;
            A = Bv; Bv = C; C = d;
        }
        #pragma unroll
        for (int m = 0; m < 9; ++m) { ct0[m] = ct1[m]; ct1[m] = ct2[m]; ct2[m] = ct3[m]; }
    }
    float3 bc, nn, m3;
    nerf_frame(A, Bv, C, bc, nn, m3);
    P.FPbuf[(frag * 12 + 0)  * 256 + bb] = bc.x;
    P.FPbuf[(frag * 12 + 1)  * 256 + bb] = bc.y;
    P.FPbuf[(frag * 12 + 2)  * 256 + bb] = bc.z;
    P.FPbuf[(frag * 12 + 3)  * 256 + bb] = m3.x;
    P.FPbuf[(frag * 12 + 4)  * 256 + bb] = m3.y;
    P.FPbuf[(frag * 12 + 5)  * 256 + bb] = m3.z;
    P.FPbuf[(frag * 12 + 6)  * 256 + bb] = nn.x;
    P.FPbuf[(frag * 12 + 7)  * 256 + bb] = nn.y;
    P.FPbuf[(frag * 12 + 8)  * 256 + bb] = nn.z;
    P.FPbuf[(frag * 12 + 9)  * 256 + bb] = C.x;
    P.FPbuf[(frag * 12 + 10) * 256 + bb] = C.y;
    P.FPbuf[(frag * 12 + 11) * 256 + bb] = C.z;
}

// ======== carry: rotation-composition over fragment constants (LDS-staged) ====
__global__ __launch_bounds__(256) void carry_kernel(KParams P) {
    __shared__ float S[384][16];
    const int tid  = threadIdx.x;
    const int base = blockIdx.x * 16;
    for (int i = tid; i < 384 * 16; i += 256) {
        int row = i >> 4, col = i & 15;
        S[row][col] = P.FPbuf[row * 256 + base + col];
    }
    __syncthreads();
    if (tid < 16) {
        int bb = base + tid;
        float3 ob = make_float3(1.f, 0.f, 0.f);
        float3 om = make_float3(0.f, 1.f, 0.f);
        float3 on = make_float3(0.f, 0.f, 1.f);
        float3 c  = make_float3(0.f, 0.f, 0.f);
        for (int f = 0; f < 32; ++f) {
            int fb = (f * 256 + bb) * 3;
            P.frames[fb + 0] = make_float4(ob.x, ob.y, ob.z, om.x);
            P.frames[fb + 1] = make_float4(om.y, om.z, on.x, on.y);
            P.frames[fb + 2] = make_float4(on.z, c.x, c.y, c.z);

            int r0 = f * 12;
            float3 Fb = make_float3(S[r0+0][tid], S[r0+1][tid], S[r0+2][tid]);
            float3 Fm = make_float3(S[r0+3][tid], S[r0+4][tid], S[r0+5][tid]);
            float3 Fn = make_float3(S[r0+6][tid], S[r0+7][tid], S[r0+8][tid]);
            float3 p  = make_float3(S[r0+9][tid], S[r0+10][tid], S[r0+11][tid]);

            float3 nb = make_float3(
                fmaf(ob.x,Fb.x, fmaf(om.x,Fb.y, on.x*Fb.z)),
                fmaf(ob.y,Fb.x, fmaf(om.y,Fb.y, on.y*Fb.z)),
                fmaf(ob.z,Fb.x, fmaf(om.z,Fb.y, on.z*Fb.z)));
            float3 nm = make_float3(
                fmaf(ob.x,Fm.x, fmaf(om.x,Fm.y, on.x*Fm.z)),
                fmaf(ob.y,Fm.x, fmaf(om.y,Fm.y, on.y*Fm.z)),
                fmaf(ob.z,Fm.x, fmaf(om.z,Fm.y, on.z*Fm.z)));
            float3 nn2 = make_float3(
                fmaf(ob.x,Fn.x, fmaf(om.x,Fn.y, on.x*Fn.z)),
                fmaf(ob.y,Fn.x, fmaf(om.y,Fn.y, on.y*Fn.z)),
                fmaf(ob.z,Fn.x, fmaf(om.z,Fn.y, on.z*Fn.z)));
            float3 nc = make_float3(
                fmaf(ob.x,p.x, fmaf(om.x,p.y, fmaf(on.x,p.z, c.x))),
                fmaf(ob.y,p.x, fmaf(om.y,p.y, fmaf(on.y,p.z, c.y))),
                fmaf(ob.z,p.x, fmaf(om.z,p.y, fmaf(on.z,p.z, c.z))));
            ob = nb; om = nm; on = nn2; c = nc;
        }
    }
}

// ======== apply: 4 rows/block; LDS-staged coalesced output ========
__global__ __launch_bounds__(256) void apply_kernel(KParams P) {
    __shared__ float sm[768];
    const int bb = threadIdx.x;
    #pragma unroll 1
    for (int i = 0; i < 4; ++i) {
        const int row  = blockIdx.x * 4 + i;
        const int frag = row / 96;

        float fx = P.fragbuf[(row * 3 + 0) * 256 + bb];
        float fy = P.fragbuf[(row * 3 + 1) * 256 + bb];
        float fz = P.fragbuf[(row * 3 + 2) * 256 + bb];

        int fb = (frag * 256 + bb) * 3;
        float4 f0 = P.frames[fb + 0];
        float4 f1 = P.frames[fb + 1];
        float4 f2 = P.frames[fb + 2];

        float ox = f2.y + f0.x * fx + f0.w * fy + f1.z * fz;
        float oy = f2.z + f0.y * fx + f1.x * fy + f1.w * fz;
        float oz = f2.w + f0.z * fx + f1.y * fy + f2.x * fz;

        __syncthreads();   // prior iteration's sm reads complete
        sm[bb * 3 + 0] = ox;
        sm[bb * 3 + 1] = oy;
        sm[bb * 3 + 2] = oz;
        __syncthreads();

        int base = row * 768;
        P.out[base + bb]       = sm[bb];
        P.out[base + 256 + bb] = sm[256 + bb];
        P.out[base + 512 + bb] = sm[512 + bb];
    }
}

// ======== host launch: 5-dispatch path (coop fusion measured 2.3x worse:
// grid.sync ~90us each on 8-XCD MI355X — r10) ========
extern "C" void kernel_launch(void* const* d_in, const int* in_sizes, int n_in,
                              void* d_out, int out_size, void* d_ws, size_t ws_size,
                              hipStream_t stream) {
    float* ws      = (float*)d_ws;
    float* kmerT   = ws;                       // 10648*64 = 681472
    float* seqT    = kmerT + 681472;           // 1280
    float* srf_t   = seqT + 1280;              // 2359296
    float* fragbuf = srf_t + 2359296;          // 2359296
    float* frames  = fragbuf + 2359296;        // 98304 (float4-accessed)
    float* FPbuf   = frames + 98304;           // 98304

    // split weight tables alias fragbuf (tables writes -> mlp reads -> extend
    // overwrites; strictly ordered by kernel boundaries)
    unsigned short* WeTH  = (unsigned short*)fragbuf;
    unsigned short* WeTL  = WeTH + 4096;
    unsigned short* W0pTH = WeTL + 4096;
    unsigned short* W0pTL = W0pTH + 2048;
    unsigned short* W1TH  = W0pTL + 2048;
    unsigned short* W1TL  = W1TH + 1024;

    KParams P;
    P.seq  = (const int*)d_in[0];
    P.kmer = (const int*)d_in[1];
    P.pssm = (const float*)d_in[2];
    P.se   = (const float*)d_in[4];
    P.emb  = (const float*)d_in[5];
    P.W0   = (const float*)d_in[6];
    P.b0   = (const float*)d_in[7];
    P.We   = (const float*)d_in[8];
    P.be   = (const float*)d_in[9];
    P.W1   = (const float*)d_in[10];
    P.b1   = (const float*)d_in[11];
    P.kmerT = kmerT; P.seqT = seqT; P.srf_t = srf_t; P.fragbuf = fragbuf;
    P.frames = (float4*)frames; P.FPbuf = FPbuf; P.out = (float*)d_out;
    P.WeTH = WeTH; P.WeTL = WeTL; P.W0pTH = W0pTH; P.W0pTL = W0pTL;
    P.W1TH = W1TH; P.W1TL = W1TL;

    hipLaunchKernelGGL(tables_kernel, dim3(173),  dim3(256), 0, stream, P);
    hipLaunchKernelGGL(mlp_kernel,    dim3(4096), dim3(256), 0, stream, P);
    hipLaunchKernelGGL(extend_kernel, dim3(128),  dim3(64),  0, stream, P);
    hipLaunchKernelGGL(carry_kernel,  dim3(16),   dim3(256), 0, stream, P);
    hipLaunchKernelGGL(apply_kernel,  dim3(768),  dim3(256), 0, stream, P);
}

// Round 14
// 175.912 us; speedup vs baseline: 1.1059x; 1.1059x over previous
//
#include <hip/hip_runtime.h>
#include <math.h>

typedef short bf16x8 __attribute__((ext_vector_type(8)));
typedef float f32x4  __attribute__((ext_vector_type(4)));

// round-to-nearest-even float -> bf16 bits
__device__ __forceinline__ unsigned short f2bf(float x) {
    unsigned int u = __float_as_uint(x);
    return (unsigned short)((u + 0x7FFFu + ((u >> 16) & 1u)) >> 16);
}
__device__ __forceinline__ float bf2f(unsigned short h) {
    return __uint_as_float(((unsigned int)h) << 16);
}
// RNE split (precompute path)
__device__ __forceinline__ void split2(float x, unsigned short& h, unsigned short& l) {
    h = f2bf(x);
    l = f2bf(x - bf2f(h));
}
// truncation split (hot path): hi = trunc(x), lo = RNE(x-hi); combined rel err ~2^-17
__device__ __forceinline__ void split2t(float x, unsigned short& h, unsigned short& l) {
    unsigned int u = __float_as_uint(x);
    h = (unsigned short)(u >> 16);
    float r = x - __uint_as_float(u & 0xFFFF0000u);
    l = f2bf(r);
}

// XOR-swizzled H index (shorts): row stride 72 shorts (144 B, 16B-aligned rows).
__device__ __forceinline__ int hsw(int row, int col) {
    return row * 72 + ((((col >> 3) ^ ((row >> 2) & 3)) << 3) | (col & 7));
}

__device__ __forceinline__ float inv_norm3(float x, float y, float z) {
    float d = fmaf(x, x, fmaf(y, y, z * z));
    return rsqrtf(fmaxf(d, 1e-24f));
}
__device__ __forceinline__ float3 f3sub(float3 a, float3 b) {
    return make_float3(a.x - b.x, a.y - b.y, a.z - b.z);
}
__device__ __forceinline__ float3 f3cross(float3 a, float3 b) {
    return make_float3(a.y * b.z - a.z * b.y,
                       a.z * b.x - a.x * b.z,
                       a.x * b.y - a.y * b.x);
}
// NeRF frame, parallel normalizations (n from unnormalized w: same direction)
__device__ __forceinline__ void nerf_frame(const float3& A, const float3& Bv,
                                           const float3& C, float3& bc,
                                           float3& n, float3& m3) {
    float3 w  = f3sub(C, Bv);
    float3 v  = f3sub(Bv, A);
    float3 cr = f3cross(v, w);
    float iw = inv_norm3(w.x, w.y, w.z);
    float ic = inv_norm3(cr.x, cr.y, cr.z);
    bc = make_float3(w.x * iw, w.y * iw, w.z * iw);
    n  = make_float3(cr.x * ic, cr.y * ic, cr.z * ic);
    m3 = f3cross(n, bc);
}
__device__ __forceinline__ float3 nerf_place(const float3& C, const float3& bc,
                                             const float3& m3, const float3& n,
                                             float tx, float ty, float tz) {
    return make_float3(
        fmaf(m3.x, ty, fmaf(bc.x, tx, fmaf(n.x, tz, C.x))),
        fmaf(m3.y, ty, fmaf(bc.y, tx, fmaf(n.y, tz, C.y))),
        fmaf(m3.z, ty, fmaf(bc.z, tx, fmaf(n.z, tz, C.z))));
}

struct KParams {
    const int* seq; const int* kmer; const float* pssm;
    const float* se; const float* emb;
    const float* W0; const float* b0; const float* We; const float* be;
    const float* W1; const float* b1;
    float* kmerT; float* seqT; float* srf_t; float* fragbuf;
    float4* frames; float* FPbuf; float* out;
    unsigned short *WeTH, *WeTL, *W0pTH, *W0pTL, *W1TH, *W1TL;
};

// ======== tables: kmerT via split-bf16 MFMA (vector loads), seqT, weight tables
__global__ __launch_bounds__(256) void tables_kernel(KParams P) {
    const int tid = threadIdx.x;
    const int vb  = blockIdx.x;
    if (vb < 167) {
        const int lane = tid & 63;
        const int wv   = __builtin_amdgcn_readfirstlane(tid >> 6);
        const int q    = lane >> 4;
        const int c16  = lane & 15;
        const int r0   = vb * 64;
        const int n    = wv * 16 + c16;

        bf16x8 BH[8], BL[8];
        #pragma unroll
        for (int kt8 = 0; kt8 < 8; ++kt8)
            #pragma unroll
            for (int j = 0; j < 8; ++j) {
                float w = P.W0[(16 + kt8 * 32 + q * 8 + j) * 64 + n];
                unsigned short h, l; split2t(w, h, l);
                BH[kt8][j] = (short)h; BL[kt8][j] = (short)l;
            }
        f32x4 acc[4];
        #pragma unroll
        for (int t = 0; t < 4; ++t) acc[t] = (f32x4){0.f, 0.f, 0.f, 0.f};
        #pragma unroll
        for (int kt8 = 0; kt8 < 8; ++kt8) {
            #pragma unroll
            for (int t = 0; t < 4; ++t) {
                int rr = r0 + t * 16 + c16;
                if (rr > 10647) rr = 10647;
                const float* ap = P.emb + rr * 256 + kt8 * 32 + q * 8;
                float4 a0 = *(const float4*)ap;
                float4 a1 = *(const float4*)(ap + 4);
                bf16x8 ah, al;
                unsigned short h, l;
                split2t(a0.x, h, l); ah[0] = (short)h; al[0] = (short)l;
                split2t(a0.y, h, l); ah[1] = (short)h; al[1] = (short)l;
                split2t(a0.z, h, l); ah[2] = (short)h; al[2] = (short)l;
                split2t(a0.w, h, l); ah[3] = (short)h; al[3] = (short)l;
                split2t(a1.x, h, l); ah[4] = (short)h; al[4] = (short)l;
                split2t(a1.y, h, l); ah[5] = (short)h; al[5] = (short)l;
                split2t(a1.z, h, l); ah[6] = (short)h; al[6] = (short)l;
                split2t(a1.w, h, l); ah[7] = (short)h; al[7] = (short)l;
                acc[t] = __builtin_amdgcn_mfma_f32_16x16x32_bf16(ah, BH[kt8], acc[t], 0, 0, 0);
                acc[t] = __builtin_amdgcn_mfma_f32_16x16x32_bf16(al, BH[kt8], acc[t], 0, 0, 0);
                acc[t] = __builtin_amdgcn_mfma_f32_16x16x32_bf16(ah, BL[kt8], acc[t], 0, 0, 0);
            }
        }
        #pragma unroll
        for (int t = 0; t < 4; ++t)
            #pragma unroll
            for (int r = 0; r < 4; ++r) {
                int row = r0 + t * 16 + q * 4 + r;
                if (row < 10648) P.kmerT[row * 64 + n] = acc[t][r];
            }
    } else if (vb < 172) {
        // seqT[r][j] = seq_embed[r]@W0[0:16] + b0[j] + 0.5*sum_c W0p[c][j]
        int e = (vb - 167) * 256 + tid;
        int r = e >> 6, j = e & 63;
        float acc = P.b0[j];
        #pragma unroll
        for (int k = 0; k < 16; ++k)
            acc = fmaf(P.se[r * 16 + k], P.W0[k * 64 + j], acc);
        float cs = 0.f;
        #pragma unroll
        for (int c = 0; c < 21; ++c) cs += P.W0[(272 + c) * 64 + j];
        P.seqT[r * 64 + j] = acc + 0.5f * cs;
    } else {
        #pragma unroll
        for (int i = 0; i < 16; ++i) {
            int e = i * 256 + tid;
            int k = e >> 6, n = e & 63;
            unsigned short h, l; split2(P.We[k * 64 + n], h, l);
            P.WeTH[n * 64 + k] = h; P.WeTL[n * 64 + k] = l;
        }
        #pragma unroll
        for (int i = 0; i < 8; ++i) {
            int e = i * 256 + tid;
            int k = e >> 6, n = e & 63;
            float w = (k < 21) ? P.W0[(272 + k) * 64 + n] : 0.f;
            unsigned short h, l; split2(w, h, l);
            P.W0pTH[n * 32 + k] = h; P.W0pTL[n * 32 + k] = l;
        }
        #pragma unroll
        for (int i = 0; i < 4; ++i) {
            int e = i * 256 + tid;
            int k = e >> 4, c = e & 15;
            float w = (c < 9) ? P.W1[k * 9 + c] : 0.f;
            unsigned short h, l; split2(w, h, l);
            P.W1TH[c * 64 + k] = h; P.W1TL[c * 64 + k] = l;
        }
    }
}

// ======== split-bf16 MFMA MLP (r12: N-split, LDS-staged, best-measured 47us) ==
__global__ __launch_bounds__(256, 4) void mlp_kernel(KParams P) {
    __shared__ __align__(16) unsigned char SMEM[36864];
    unsigned short* Hah = (unsigned short*)(SMEM);           // swizzled, 9216 B
    unsigned short* Hal = (unsigned short*)(SMEM + 9216);
    unsigned short* Hbh = (unsigned short*)(SMEM + 18432);
    unsigned short* Hbl = (unsigned short*)(SMEM + 27648);
    unsigned short (*Ph)[40] = (unsigned short (*)[40])(SMEM + 18432);  // overlay
    unsigned short (*Pl)[40] = (unsigned short (*)[40])(SMEM + 18432 + 5120);

    const int tid  = threadIdx.x;
    const int lane = tid & 63;
    const int wv   = __builtin_amdgcn_readfirstlane(tid >> 6);
    const int q    = lane >> 4;
    const int c16  = lane & 15;
    const int m0   = blockIdx.x * 64;
    const int n    = wv * 16 + c16;

    // ---- indices: one coalesced load per lane, redistribute via bpermute;
    //      gathers issue immediately (no barrier dependency) ----
    const int myseq = P.seq[m0 + lane];
    const int mykm  = P.kmer[m0 + lane];
    float g[4][4];
    #pragma unroll
    for (int t = 0; t < 4; ++t)
        #pragma unroll
        for (int r = 0; r < 4; ++r) {
            int src = (t * 16 + q * 4 + r) << 2;
            int s  = __builtin_amdgcn_ds_bpermute(src, myseq);
            int km = __builtin_amdgcn_ds_bpermute(src, mykm);
            g[t][r] = P.seqT[s * 64 + n] + P.kmerT[km * 64 + n];
        }

    // ---- stage centered pssm (trunc-split) into LDS overlay ----
    for (int i = tid; i < 64 * 21; i += 256) {
        float v = P.pssm[m0 * 21 + i] - 0.5f;
        unsigned short h, l; split2t(v, h, l);
        Ph[i / 21][i % 21] = h;
        Pl[i / 21][i % 21] = l;
    }
    for (int i = tid; i < 64 * 11; i += 256) {
        Ph[i / 11][21 + (i % 11)] = 0;
        Pl[i / 11][21 + (i % 11)] = 0;
    }

    // ---- weight fragments + biases (L1/L2-hot 16B loads) ----
    bf16x8 WeH[2], WeL[2], W1H[2], W1L[2], W0H, W0L;
    #pragma unroll
    for (int kk = 0; kk < 2; ++kk) {
        WeH[kk] = *(const bf16x8*)(P.WeTH + n * 64 + kk * 32 + q * 8);
        WeL[kk] = *(const bf16x8*)(P.WeTL + n * 64 + kk * 32 + q * 8);
        W1H[kk] = *(const bf16x8*)(P.W1TH + c16 * 64 + kk * 32 + q * 8);
        W1L[kk] = *(const bf16x8*)(P.W1TL + c16 * 64 + kk * 32 + q * 8);
    }
    W0H = *(const bf16x8*)(P.W0pTH + n * 32 + q * 8);
    W0L = *(const bf16x8*)(P.W0pTL + n * 32 + q * 8);
    const float be_n = P.be[n];
    const float b1h  = (c16 < 9) ? P.b1[c16] : 0.f;
    __syncthreads();

    // ---- layer 0: zero-init MFMA, then add gathers late ----
    f32x4 acc[4];
    #pragma unroll
    for (int t = 0; t < 4; ++t) acc[t] = (f32x4){0.f, 0.f, 0.f, 0.f};
    #pragma unroll
    for (int t = 0; t < 4; ++t) {
        bf16x8 ah = *(const bf16x8*)&Ph[t * 16 + c16][q * 8];
        bf16x8 al = *(const bf16x8*)&Pl[t * 16 + c16][q * 8];
        acc[t] = __builtin_amdgcn_mfma_f32_16x16x32_bf16(ah, W0H, acc[t], 0, 0, 0);
        acc[t] = __builtin_amdgcn_mfma_f32_16x16x32_bf16(al, W0H, acc[t], 0, 0, 0);
        acc[t] = __builtin_amdgcn_mfma_f32_16x16x32_bf16(ah, W0L, acc[t], 0, 0, 0);
    }
    #pragma unroll
    for (int t = 0; t < 4; ++t)
        #pragma unroll
        for (int r = 0; r < 4; ++r) {
            unsigned short h, l; split2t(acc[t][r] + g[t][r], h, l);
            Hah[hsw(t * 16 + q * 4 + r, n)] = h;
            Hal[hsw(t * 16 + q * 4 + r, n)] = l;
        }
    __syncthreads();   // h0 ready; pssm reads done -> Hb overlay reusable

    // ---- layer 1: Ha -> Hb (relu) ----
    {
        f32x4 a1[4];
        #pragma unroll
        for (int t = 0; t < 4; ++t) {
            a1[t] = (f32x4){be_n, be_n, be_n, be_n};
            #pragma unroll
            for (int kk = 0; kk < 2; ++kk) {
                bf16x8 ah = *(const bf16x8*)&Hah[hsw(t * 16 + c16, kk * 32 + q * 8)];
                bf16x8 al = *(const bf16x8*)&Hal[hsw(t * 16 + c16, kk * 32 + q * 8)];
                a1[t] = __builtin_amdgcn_mfma_f32_16x16x32_bf16(ah, WeH[kk], a1[t], 0, 0, 0);
                a1[t] = __builtin_amdgcn_mfma_f32_16x16x32_bf16(al, WeH[kk], a1[t], 0, 0, 0);
                a1[t] = __builtin_amdgcn_mfma_f32_16x16x32_bf16(ah, WeL[kk], a1[t], 0, 0, 0);
            }
        }
        #pragma unroll
        for (int t = 0; t < 4; ++t)
            #pragma unroll
            for (int r = 0; r < 4; ++r) {
                unsigned short h, l; split2t(fmaxf(a1[t][r], 0.f), h, l);
                Hbh[hsw(t * 16 + q * 4 + r, n)] = h;
                Hbl[hsw(t * 16 + q * 4 + r, n)] = l;
            }
        __syncthreads();
    }
    // ---- layer 2: Hb -> Ha (relu) ----
    {
        f32x4 a2[4];
        #pragma unroll
        for (int t = 0; t < 4; ++t) {
            a2[t] = (f32x4){be_n, be_n, be_n, be_n};
            #pragma unroll
            for (int kk = 0; kk < 2; ++kk) {
                bf16x8 ah = *(const bf16x8*)&Hbh[hsw(t * 16 + c16, kk * 32 + q * 8)];
                bf16x8 al = *(const bf16x8*)&Hbl[hsw(t * 16 + c16, kk * 32 + q * 8)];
                a2[t] = __builtin_amdgcn_mfma_f32_16x16x32_bf16(ah, WeH[kk], a2[t], 0, 0, 0);
                a2[t] = __builtin_amdgcn_mfma_f32_16x16x32_bf16(al, WeH[kk], a2[t], 0, 0, 0);
                a2[t] = __builtin_amdgcn_mfma_f32_16x16x32_bf16(ah, WeL[kk], a2[t], 0, 0, 0);
            }
        }
        #pragma unroll
        for (int t = 0; t < 4; ++t)
            #pragma unroll
            for (int r = 0; r < 4; ++r) {
                unsigned short h, l; split2t(fmaxf(a2[t][r], 0.f), h, l);
                Hah[hsw(t * 16 + q * 4 + r, n)] = h;
                Hal[hsw(t * 16 + q * 4 + r, n)] = l;
            }
        __syncthreads();
    }
    // ---- head: wave wv does M-tile wv ----
    {
        f32x4 ah4 = (f32x4){b1h, b1h, b1h, b1h};
        #pragma unroll
        for (int kk = 0; kk < 2; ++kk) {
            bf16x8 ah = *(const bf16x8*)&Hah[hsw(wv * 16 + c16, kk * 32 + q * 8)];
            bf16x8 al = *(const bf16x8*)&Hal[hsw(wv * 16 + c16, kk * 32 + q * 8)];
            ah4 = __builtin_amdgcn_mfma_f32_16x16x32_bf16(ah, W1H[kk], ah4, 0, 0, 0);
            ah4 = __builtin_amdgcn_mfma_f32_16x16x32_bf16(al, W1H[kk], ah4, 0, 0, 0);
            ah4 = __builtin_amdgcn_mfma_f32_16x16x32_bf16(ah, W1L[kk], ah4, 0, 0, 0);
        }
        if (c16 < 9) {
            #pragma unroll
            for (int r = 0; r < 4; ++r) {
                int pos = m0 + wv * 16 + q * 4 + r;
                int l = pos >> 8, b = pos & 255;
                P.srf_t[(l * 9 + c16) * 256 + b] = ah4[r];
            }
        }
    }
}

// ======== extend: depth-3 prefetch; emits per-fragment frame + endpoint ========
__global__ __launch_bounds__(64) void extend_kernel(KParams P) {
    int frag = blockIdx.x >> 2;
    int bb   = ((blockIdx.x & 3) << 6) + threadIdx.x;

    float3 A  = make_float3(-0.70710678118654752f, 1.22474487139158905f, 0.f);
    float3 Bv = make_float3(-1.41421356237309505f, 0.f, 0.f);
    float3 C  = make_float3(0.f, 0.f, 0.f);

    float ct0[9], ct1[9], ct2[9], ct3[9];
    #pragma unroll
    for (int m = 0; m < 9; ++m) {
        ct0[m] = P.srf_t[((frag * 32 + 0) * 9 + m) * 256 + bb];
        ct1[m] = P.srf_t[((frag * 32 + 1) * 9 + m) * 256 + bb];
        ct2[m] = P.srf_t[((frag * 32 + 2) * 9 + m) * 256 + bb];
    }
    for (int ll = 0; ll < 32; ++ll) {
        if (ll < 29) {
            #pragma unroll
            for (int m = 0; m < 9; ++m)
                ct3[m] = P.srf_t[((frag * 32 + ll + 3) * 9 + m) * 256 + bb];
        } else {
            #pragma unroll
            for (int m = 0; m < 9; ++m) ct3[m] = 0.f;
        }
        #pragma unroll
        for (int s3 = 0; s3 < 3; ++s3) {
            float3 bc, nn, m3;
            nerf_frame(A, Bv, C, bc, nn, m3);
            float3 d = nerf_place(C, bc, m3, nn,
                                  ct0[3 * s3 + 0], ct0[3 * s3 + 1], ct0[3 * s3 + 2]);
            int row = frag * 96 + ll * 3 + s3;
            P.fragbuf[(row * 3 + 0) * 256 + bb] = d.x;
            P.fragbuf[(row * 3 + 1) * 256 + bb] = d.y;
            P.fragbuf[(row * 3 + 2) * 256 + bb] = d.z;
            A = Bv; Bv = C; C = d;
        }
        #pragma unroll
        for (int m = 0; m < 9; ++m) { ct0[m] = ct1[m]; ct1[m] = ct2[m]; ct2[m] = ct3[m]; }
    }
    float3 bc, nn, m3;
    nerf_frame(A, Bv, C, bc, nn, m3);
    P.FPbuf[(frag * 12 + 0)  * 256 + bb] = bc.x;
    P.FPbuf[(frag * 12 + 1)  * 256 + bb] = bc.y;
    P.FPbuf[(frag * 12 + 2)  * 256 + bb] = bc.z;
    P.FPbuf[(frag * 12 + 3)  * 256 + bb] = m3.x;
    P.FPbuf[(frag * 12 + 4)  * 256 + bb] = m3.y;
    P.FPbuf[(frag * 12 + 5)  * 256 + bb] = m3.z;
    P.FPbuf[(frag * 12 + 6)  * 256 + bb] = nn.x;
    P.FPbuf[(frag * 12 + 7)  * 256 + bb] = nn.y;
    P.FPbuf[(frag * 12 + 8)  * 256 + bb] = nn.z;
    P.FPbuf[(frag * 12 + 9)  * 256 + bb] = C.x;
    P.FPbuf[(frag * 12 + 10) * 256 + bb] = C.y;
    P.FPbuf[(frag * 12 + 11) * 256 + bb] = C.z;
}

// ======== carry: rotation-composition over fragment constants (LDS-staged) ====
__global__ __launch_bounds__(256) void carry_kernel(KParams P) {
    __shared__ float S[384][16];
    const int tid  = threadIdx.x;
    const int base = blockIdx.x * 16;
    for (int i = tid; i < 384 * 16; i += 256) {
        int row = i >> 4, col = i & 15;
        S[row][col] = P.FPbuf[row * 256 + base + col];
    }
    __syncthreads();
    if (tid < 16) {
        int bb = base + tid;
        float3 ob = make_float3(1.f, 0.f, 0.f);
        float3 om = make_float3(0.f, 1.f, 0.f);
        float3 on = make_float3(0.f, 0.f, 1.f);
        float3 c  = make_float3(0.f, 0.f, 0.f);
        for (int f = 0; f < 32; ++f) {
            int fb = (f * 256 + bb) * 3;
            P.frames[fb + 0] = make_float4(ob.x, ob.y, ob.z, om.x);
            P.frames[fb + 1] = make_float4(om.y, om.z, on.x, on.y);
            P.frames[fb + 2] = make_float4(on.z, c.x, c.y, c.z);

            int r0 = f * 12;
            float3 Fb = make_float3(S[r0+0][tid], S[r0+1][tid], S[r0+2][tid]);
            float3 Fm = make_float3(S[r0+3][tid], S[r0+4][tid], S[r0+5][tid]);
            float3 Fn = make_float3(S[r0+6][tid], S[r0+7][tid], S[r0+8][tid]);
            float3 p  = make_float3(S[r0+9][tid], S[r0+10][tid], S[r0+11][tid]);

            float3 nb = make_float3(
                fmaf(ob.x,Fb.x, fmaf(om.x,Fb.y, on.x*Fb.z)),
                fmaf(ob.y,Fb.x, fmaf(om.y,Fb.y, on.y*Fb.z)),
                fmaf(ob.z,Fb.x, fmaf(om.z,Fb.y, on.z*Fb.z)));
            float3 nm = make_float3(
                fmaf(ob.x,Fm.x, fmaf(om.x,Fm.y, on.x*Fm.z)),
                fmaf(ob.y,Fm.x, fmaf(om.y,Fm.y, on.y*Fm.z)),
                fmaf(ob.z,Fm.x, fmaf(om.z,Fm.y, on.z*Fm.z)));
            float3 nn2 = make_float3(
                fmaf(ob.x,Fn.x, fmaf(om.x,Fn.y, on.x*Fn.z)),
                fmaf(ob.y,Fn.x, fmaf(om.y,Fn.y, on.y*Fn.z)),
                fmaf(ob.z,Fn.x, fmaf(om.z,Fn.y, on.z*Fn.z)));
            float3 nc = make_float3(
                fmaf(ob.x,p.x, fmaf(om.x,p.y, fmaf(on.x,p.z, c.x))),
                fmaf(ob.y,p.x, fmaf(om.y,p.y, fmaf(on.y,p.z, c.y))),
                fmaf(ob.z,p.x, fmaf(om.z,p.y, fmaf(on.z,p.z, c.z))));
            ob = nb; om = nm; on = nn2; c = nc;
        }
    }
}

// ======== apply: 4 rows/block; LDS-staged coalesced output ========
__global__ __launch_bounds__(256) void apply_kernel(KParams P) {
    __shared__ float sm[768];
    const int bb = threadIdx.x;
    #pragma unroll 1
    for (int i = 0; i < 4; ++i) {
        const int row  = blockIdx.x * 4 + i;
        const int frag = row / 96;

        float fx = P.fragbuf[(row * 3 + 0) * 256 + bb];
        float fy = P.fragbuf[(row * 3 + 1) * 256 + bb];
        float fz = P.fragbuf[(row * 3 + 2) * 256 + bb];

        int fb = (frag * 256 + bb) * 3;
        float4 f0 = P.frames[fb + 0];
        float4 f1 = P.frames[fb + 1];
        float4 f2 = P.frames[fb + 2];

        float ox = f2.y + f0.x * fx + f0.w * fy + f1.z * fz;
        float oy = f2.z + f0.y * fx + f1.x * fy + f1.w * fz;
        float oz = f2.w + f0.z * fx + f1.y * fy + f2.x * fz;

        __syncthreads();   // prior iteration's sm reads complete
        sm[bb * 3 + 0] = ox;
        sm[bb * 3 + 1] = oy;
        sm[bb * 3 + 2] = oz;
        __syncthreads();

        int base = row * 768;
        P.out[base + bb]       = sm[bb];
        P.out[base + 256 + bb] = sm[256 + bb];
        P.out[base + 512 + bb] = sm[512 + bb];
    }
}

// ======== host launch: 5-dispatch path (coop fusion measured 2.3x worse:
// grid.sync ~90us each on 8-XCD MI355X — r10) ========
extern "C" void kernel_launch(void* const* d_in, const int* in_sizes, int n_in,
                              void* d_out, int out_size, void* d_ws, size_t ws_size,
                              hipStream_t stream) {
    float* ws      = (float*)d_ws;
    float* kmerT   = ws;                       // 10648*64 = 681472
    float* seqT    = kmerT + 681472;           // 1280
    float* srf_t   = seqT + 1280;              // 2359296
    float* fragbuf = srf_t + 2359296;          // 2359296
    float* frames  = fragbuf + 2359296;        // 98304 (float4-accessed)
    float* FPbuf   = frames + 98304;           // 98304

    // split weight tables alias fragbuf (tables writes -> mlp reads -> extend
    // overwrites; strictly ordered by kernel boundaries)
    unsigned short* WeTH  = (unsigned short*)fragbuf;
    unsigned short* WeTL  = WeTH + 4096;
    unsigned short* W0pTH = WeTL + 4096;
    unsigned short* W0pTL = W0pTH + 2048;
    unsigned short* W1TH  = W0pTL + 2048;
    unsigned short* W1TL  = W1TH + 1024;

    KParams P;
    P.seq  = (const int*)d_in[0];
    P.kmer = (const int*)d_in[1];
    P.pssm = (const float*)d_in[2];
    P.se   = (const float*)d_in[4];
    P.emb  = (const float*)d_in[5];
    P.W0   = (const float*)d_in[6];
    P.b0   = (const float*)d_in[7];
    P.We   = (const float*)d_in[8];
    P.be   = (const float*)d_in[9];
    P.W1   = (const float*)d_in[10];
    P.b1   = (const float*)d_in[11];
    P.kmerT = kmerT; P.seqT = seqT; P.srf_t = srf_t; P.fragbuf = fragbuf;
    P.frames = (float4*)frames; P.FPbuf = FPbuf; P.out = (float*)d_out;
    P.WeTH = WeTH; P.WeTL = WeTL; P.W0pTH = W0pTH; P.W0pTL = W0pTL;
    P.W1TH = W1TH; P.W1TL = W1TL;

    hipLaunchKernelGGL(tables_kernel, dim3(173),  dim3(256), 0, stream, P);
    hipLaunchKernelGGL(mlp_kernel,    dim3(4096), dim3(256), 0, stream, P);
    hipLaunchKernelGGL(extend_kernel, dim3(128),  dim3(64),  0, stream, P);
    hipLaunchKernelGGL(carry_kernel,  dim3(16),   dim3(256), 0, stream, P);
    hipLaunchKernelGGL(apply_kernel,  dim3(768),  dim3(256), 0, stream, P);
}